// Round 4
// baseline (405.587 us; speedup 1.0000x reference)
//
#include <hip/hip_runtime.h>
#include <cstdint>

#define NB 16
#define NCL 80
#define KDIM 85
#define NA 25200
#define NBINS 1024
#define CAP 2048
#define MAXN 1024
#define NDET 300
#define NSLAB 396
#define SLOTS 416

// per (lvl*3+ai) segment tables
__device__ __constant__ float c_ancw[9] = {10.f,16.f,33.f, 30.f,62.f,59.f, 116.f,156.f,373.f};
__device__ __constant__ float c_anch[9] = {13.f,30.f,23.f, 61.f,45.f,119.f, 90.f,198.f,326.f};
__device__ __constant__ int   c_seg_a0[9]    = {0,6400,12800,19200,20800,22400,24000,24400,24800};
__device__ __constant__ int   c_seg_cells[9] = {6400,6400,6400,1600,1600,1600,400,400,400};
__device__ __constant__ int   c_seg_ww[9]    = {80,80,80,40,40,40,20,20,20};
__device__ __constant__ float c_seg_str[9]   = {8.f,8.f,8.f,16.f,16.f,16.f,32.f,32.f,32.f};
__device__ __constant__ int   c_seg_slab0[9] = {0,100,200,300,325,350,375,382,389};

__device__ __forceinline__ float sgm(float x) { return 1.0f / (1.0f + expf(-x)); }
__device__ __forceinline__ int binof(float s) {
  int b = (int)((s - 0.25f) * 1365.3334f);   // NBINS / 0.75
  return b < 0 ? 0 : (b > NBINS - 1 ? NBINS - 1 : b);
}

struct Loc { const float* base; };
__device__ __forceinline__ Loc locate(const float* h0, const float* h1, const float* h2,
                                      int img, int a) {
  Loc L; const float* hp; int cells, rel;
  if (a < 19200)      { hp=h0; cells=6400; rel=a;       }
  else if (a < 24000) { hp=h1; cells=1600; rel=a-19200; }
  else                { hp=h2; cells=400;  rel=a-24000; }
  int ai = rel / cells; int cell = rel - ai*cells;
  L.base = hp + (size_t)((img*3 + ai)*cells + cell) * KDIM;
  return L;
}

// ---- K1: LDS-staged decode: boxes + sobj + per-image score histogram ----
__global__ void __launch_bounds__(256) k_decode(const float* __restrict__ h0,
    const float* __restrict__ h1, const float* __restrict__ h2,
    float* __restrict__ boxes, float* __restrict__ sobjv, unsigned* __restrict__ hist) {
  __shared__ unsigned lh[NBINS];
  __shared__ float buf[64 * KDIM];
  int tid = threadIdx.x, img = blockIdx.y;
  for (int i = tid; i < NBINS; i += 256) lh[i] = 0;
  __syncthreads();
  for (int sl = 0; sl < 4; ++sl) {
    int slab = blockIdx.x * 4 + sl;          // grid.x*4 == NSLAB exactly
    int sg = 0;
    #pragma unroll
    for (int k = 1; k < 9; ++k) sg += (slab >= c_seg_slab0[k]);
    int sloc  = slab - c_seg_slab0[sg];
    int cells = c_seg_cells[sg];
    int c0    = sloc * 64;
    int ncell = min(64, cells - c0);
    const float* hp = (sg < 3) ? h0 : (sg < 6 ? h1 : h2);
    int ai = sg - (sg / 3) * 3;
    const float* src = hp + (size_t)((img*3 + ai)*cells + c0) * KDIM;
    int nf = ncell * KDIM;
    __syncthreads();                          // previous slab's readers done
    for (int i = tid; i < nf; i += 256) buf[i] = src[i];
    __syncthreads();
    int anc = tid >> 2, sub = tid & 3;
    if (anc < ncell) {
      const float* rec = &buf[anc * KDIM];
      float so = sgm(rec[4]);
      int cell = c0 + anc;
      int a = c_seg_a0[sg] + cell;
      if (sub == 0) {
        int ww = c_seg_ww[sg];
        int y = cell / ww, x = cell - y*ww;
        float sx=sgm(rec[0]), sy=sgm(rec[1]), sw=sgm(rec[2]), sh=sgm(rec[3]);
        float st = c_seg_str[sg];
        float cx = (sx*2.0f - 0.5f + (float)x) * st;
        float cy = (sy*2.0f - 0.5f + (float)y) * st;
        float tw = sw*2.0f, th = sh*2.0f;
        float wv = (tw*tw) * c_ancw[sg];
        float hv = (th*th) * c_anch[sg];
        ((float4*)boxes)[(size_t)img*NA + a] =
            make_float4(cx - wv*0.5f, cy - hv*0.5f, cx + wv*0.5f, cy + hv*0.5f);
        sobjv[(size_t)img*NA + a] = so;
      }
      if (so > 0.25f) {
        #pragma unroll 4
        for (int k = 0; k < 20; ++k) {
          float s = sgm(rec[5 + sub*20 + k]) * so;
          if (s > 0.25f) atomicAdd(&lh[binof(s)], 1u);
        }
      }
    }
  }
  __syncthreads();
  unsigned* gh = hist + (size_t)img * NBINS;
  for (int i = tid; i < NBINS; i += 256) { unsigned v = lh[i]; if (v) atomicAdd(&gh[i], v); }
}

// ---- K2: per image, largest bin T with suffix-count >= MAXN ----
__global__ void __launch_bounds__(256) k_thresh(const unsigned* __restrict__ hist,
                                                int* __restrict__ tbin) {
  int img = blockIdx.x, t = threadIdx.x;
  const unsigned* gh = hist + (size_t)img * NBINS;
  __shared__ unsigned sc[256];
  unsigned loc[4]; unsigned s = 0;
  #pragma unroll
  for (int i = 0; i < 4; ++i) { loc[i] = gh[t*4 + i]; s += loc[i]; }
  sc[t] = s; __syncthreads();
  for (int d = 1; d < 256; d <<= 1) {
    unsigned add = (t + d < 256) ? sc[t + d] : 0u;
    __syncthreads(); sc[t] += add; __syncthreads();
  }
  unsigned inc = sc[t];
  unsigned excl = inc - s;
  if (excl < MAXN && inc >= MAXN) {
    unsigned cum = excl; int myT = 0;
    #pragma unroll
    for (int i = 3; i >= 0; --i) { cum += loc[i]; if (cum >= MAXN) { myT = t*4 + i; break; } }
    tbin[img] = myT;
  }
  if (t == 0 && sc[0] < MAXN) tbin[img] = 0;
}

// ---- K3: sobj-gated cooperative compaction ----
__global__ void __launch_bounds__(256) k_compact(const float* __restrict__ h0,
    const float* __restrict__ h1, const float* __restrict__ h2,
    const float* __restrict__ sobjv, const int* __restrict__ tbin,
    unsigned* __restrict__ ccnt, unsigned long long* __restrict__ cand) {
  int img = blockIdx.y;
  int a = blockIdx.x * 256 + threadIdx.x;
  int lane = threadIdx.x & 63;
  int T = tbin[img];
  float gthr = 0.25f + (float)(T - 1) * (0.75f / (float)NBINS);  // one-bin slack
  float so = 0.0f; bool pass = false;
  if (a < NA) { so = sobjv[(size_t)img*NA + a]; pass = so > gthr; }
  unsigned long long m = __ballot(pass);
  while (m) {
    int srcl = __builtin_ctzll(m); m &= m - 1;
    int aa   = __shfl(a, srcl);
    float sso = __shfl(so, srcl);
    Loc L = locate(h0, h1, h2, img, aa);
    for (int c = lane; c < NCL; c += 64) {
      float s = sgm(L.base[5 + c]) * sso;
      if (s > 0.25f && binof(s) >= T) {
        unsigned p = atomicAdd(&ccnt[img], 1u);
        if (p < CAP) {
          unsigned idx = (unsigned)(aa * NCL + c);
          cand[(size_t)img*CAP + p] =
              ((unsigned long long)__float_as_uint(s) << 32) | (unsigned)(~idx);
        }
      }
    }
  }
}

// ---- K4: per-image bitonic sort (desc), build top-1024 arrays ----
__global__ void __launch_bounds__(1024) k_sort(const unsigned long long* __restrict__ cand,
    const unsigned* __restrict__ ccnt, const float* __restrict__ boxes,
    float* __restrict__ tsc, int* __restrict__ tcls, float* __restrict__ traw,
    float* __restrict__ tbb, float* __restrict__ tarea,
    unsigned long long* __restrict__ keepinit) {
  __shared__ unsigned long long key[CAP];
  int img = blockIdx.x, t = threadIdx.x;
  int n = (int)min(ccnt[img], (unsigned)CAP);
  const unsigned long long* cb = cand + (size_t)img*CAP;
  key[t]        = (t < n)        ? cb[t]        : 0ull;
  key[t + 1024] = (t + 1024 < n) ? cb[t + 1024] : 0ull;
  __syncthreads();
  for (int k = 2; k <= CAP; k <<= 1) {
    for (int j = k >> 1; j > 0; j >>= 1) {
      #pragma unroll
      for (int eo = 0; eo < 2; ++eo) {
        int e = t + eo*1024;
        int l = e ^ j;
        if (l > e) {
          unsigned long long va = key[e], vb = key[l];
          bool up = (e & k) == 0;
          if (up ? (va < vb) : (va > vb)) { key[e] = vb; key[l] = va; }
        }
      }
      __syncthreads();
    }
  }
  unsigned long long kk = key[t];
  float s = __uint_as_float((unsigned)(kk >> 32));
  unsigned idx = ~(unsigned)kk;
  float b0=0,b1=0,b2=0,b3=0, bb0=0,bb1=0,bb2=0,bb3=0, ar=0; int cls=0;
  if (s > 0.0f) {
    unsigned anc = idx / NCL; cls = (int)(idx - anc*NCL);
    const float4 bp = ((const float4*)boxes)[(size_t)img*NA + anc];
    b0=bp.x; b1=bp.y; b2=bp.z; b3=bp.w;
    float off = (float)cls * 4096.0f;
    bb0=b0+off; bb1=b1+off; bb2=b2+off; bb3=b3+off;
    ar = (bb2-bb0)*(bb3-bb1);
  }
  int o = img*MAXN + t;
  tsc[o] = s; tcls[o] = cls; tarea[o] = ar;
  ((float4*)traw)[o] = make_float4(b0,b1,b2,b3);
  ((float4*)tbb)[o]  = make_float4(bb0,bb1,bb2,bb3);
  unsigned long long ball = __ballot(s > 0.0f);
  if ((t & 63) == 0) keepinit[img*16 + (t >> 6)] = ball;
}

// ---- K5: suppression bit matrix + per-row non-empty mask ----
__global__ void __launch_bounds__(256) k_iou(const float* __restrict__ tbb,
    const float* __restrict__ tarea, unsigned long long* __restrict__ sup,
    unsigned long long* __restrict__ rnz) {
  __shared__ float jx1[MAXN], jy1[MAXN], jx2[MAXN], jy2[MAXN], jar[MAXN];
  int img = blockIdx.y, t = threadIdx.x;
  const float4* bbb = (const float4*)(tbb + (size_t)img*MAXN*4);
  const float* aab = tarea + (size_t)img*MAXN;
  for (int i = t; i < MAXN; i += 256) {
    float4 v = bbb[i];
    jx1[i]=v.x; jy1[i]=v.y; jx2[i]=v.z; jy2[i]=v.w; jar[i]=aab[i];
  }
  __syncthreads();
  int il = t >> 4, c = t & 15;
  int i = blockIdx.x*16 + il;
  float x1=jx1[i], y1=jy1[i], x2=jx2[i], y2=jy2[i], ai=jar[i];
  unsigned long long bits = 0;
  for (int l = 0; l < 64; ++l) {
    int ll = (l + c) & 63;            // rotate to spread LDS banks
    int j = c*64 + ll;
    if (j > i) {
      float ltx = fmaxf(x1, jx1[j]), lty = fmaxf(y1, jy1[j]);
      float rbx = fminf(x2, jx2[j]), rby = fminf(y2, jy2[j]);
      float w = fmaxf(rbx - ltx, 0.0f), h = fmaxf(rby - lty, 0.0f);
      float inter = w*h;
      float iou = inter / (ai + jar[j] - inter + 1e-7f);
      if (iou > 0.45f) bits |= (1ull << ll);
    }
  }
  sup[((size_t)img*MAXN + i)*16 + c] = bits;
  if (bits) atomicOr(&rnz[img*16 + (i >> 6)], 1ull << (i & 63));
}

// ---- K6: LDS-staged sequential NMS + output ----
__global__ void __launch_bounds__(256) k_nms(const unsigned long long* __restrict__ keepinit,
    const unsigned long long* __restrict__ rnz, const unsigned long long* __restrict__ sup,
    const float* __restrict__ tsc, const int* __restrict__ tcls,
    const float* __restrict__ traw, float* __restrict__ out) {
  __shared__ unsigned long long rows[SLOTS*16];
  __shared__ unsigned short slotof[MAXN];
  __shared__ unsigned short rowof[SLOTS];
  __shared__ int scanbuf[256];
  __shared__ int order[MAXN];
  __shared__ unsigned long long s_rnz[16], s_keep[16];
  int img = blockIdx.x, tid = threadIdx.x;
  if (tid < 16) { s_rnz[tid] = rnz[img*16 + tid]; s_keep[tid] = keepinit[img*16 + tid]; }
  __syncthreads();
  // slot assignment: thread t covers rows 4t..4t+3
  unsigned nib = (unsigned)((s_rnz[tid >> 4] >> ((tid & 15)*4)) & 0xFull);
  int cnt4 = __popc(nib);
  scanbuf[tid] = cnt4; __syncthreads();
  for (int d = 1; d < 256; d <<= 1) {
    int add = (tid >= d) ? scanbuf[tid - d] : 0;
    __syncthreads(); scanbuf[tid] += add; __syncthreads();
  }
  int p = scanbuf[tid] - cnt4;
  #pragma unroll
  for (int k = 0; k < 4; ++k) {
    int r = tid*4 + k;
    if ((nib >> k) & 1) {
      if (p < SLOTS) { slotof[r] = (unsigned short)p; rowof[p] = (unsigned short)r; }
      else slotof[r] = 0xFFFF;
      ++p;
    } else slotof[r] = 0xFFFF;
  }
  __syncthreads();
  int nstage = min(scanbuf[255], SLOTS);
  for (int k = tid; k < nstage*16; k += 256)
    rows[k] = sup[((size_t)img*MAXN + rowof[k >> 4])*16 + (k & 15)];
  __syncthreads();
  if (tid < 64) {
    int lane = tid;
    unsigned long long keep = (lane < 16) ? s_keep[lane] : 0ull;
    unsigned long long rem  = (lane < 16) ? (s_keep[lane] & s_rnz[lane]) : 0ull;
    while (true) {
      int candi = MAXN;
      if (lane < 16 && rem) candi = lane*64 + __builtin_ctzll(rem);
      #pragma unroll
      for (int o = 32; o; o >>= 1) candi = min(candi, __shfl_xor(candi, o));
      if (candi >= MAXN) break;
      int sl = slotof[candi];
      unsigned long long row = 0;
      if (lane < 16)
        row = (sl != 0xFFFF) ? rows[sl*16 + lane]
                             : sup[((size_t)img*MAXN + candi)*16 + lane];
      keep &= ~row; rem &= ~row;
      if (lane == (candi >> 6)) rem &= ~(1ull << (candi & 63));
    }
    int cnt = (lane < 16) ? __popcll(keep) : 0;
    int inc = cnt;
    for (int d = 1; d < 64; d <<= 1) { int y = __shfl_up(inc, d); if (lane >= d) inc += y; }
    int total = __shfl(inc, 63);
    int base = inc - cnt;
    if (lane < 16) {
      unsigned long long mm = keep; int q = base;
      while (mm) { int b = __builtin_ctzll(mm); mm &= mm - 1; order[q++] = lane*64 + b; }
    }
    for (int r = lane; r < NDET; r += 64) {
      float4 fb = make_float4(0,0,0,0); float fs = 0.0f; float fl = -1.0f;
      if (r < total) {
        int o = img*MAXN + order[r];
        fs = tsc[o];
        fb = ((const float4*)traw)[o];
        fl = (float)tcls[o];
      }
      int ob = img*NDET + r;
      ((float4*)out)[ob] = fb;
      out[(size_t)NB*NDET*4 + ob] = fs;
      out[(size_t)NB*NDET*5 + ob] = fl;   // labels as FLOAT values (harness reads f32)
    }
  }
}

// ---- workspace layout (zero-init region first) ----
constexpr size_t AL(size_t x){ return (x + 255) & ~size_t(255); }
constexpr size_t OFF_HIST = 0;                                      // 16*1024*4
constexpr size_t OFF_CNT  = AL(OFF_HIST + (size_t)NB*NBINS*4);      // 16*4
constexpr size_t OFF_RNZ  = AL(OFF_CNT  + (size_t)NB*4);            // 16*16*8
constexpr size_t OFF_ZEND = AL(OFF_RNZ  + (size_t)NB*16*8);
constexpr size_t OFF_TBIN = OFF_ZEND;
constexpr size_t OFF_BOX  = AL(OFF_TBIN + (size_t)NB*4);
constexpr size_t OFF_SOBJ = AL(OFF_BOX  + (size_t)NB*NA*4*4);
constexpr size_t OFF_CAND = AL(OFF_SOBJ + (size_t)NB*NA*4);
constexpr size_t OFF_TSC  = AL(OFF_CAND + (size_t)NB*CAP*8);
constexpr size_t OFF_TCLS = AL(OFF_TSC  + (size_t)NB*MAXN*4);
constexpr size_t OFF_TRAW = AL(OFF_TCLS + (size_t)NB*MAXN*4);
constexpr size_t OFF_TBB  = AL(OFF_TRAW + (size_t)NB*MAXN*16);
constexpr size_t OFF_TAR  = AL(OFF_TBB  + (size_t)NB*MAXN*16);
constexpr size_t OFF_KEEP = AL(OFF_TAR  + (size_t)NB*MAXN*4);
constexpr size_t OFF_SUP  = AL(OFF_KEEP + (size_t)NB*16*8);

extern "C" void kernel_launch(void* const* d_in, const int* in_sizes, int n_in,
                              void* d_out, int out_size, void* d_ws, size_t ws_size,
                              hipStream_t stream) {
  const float *h0=nullptr,*h1=nullptr,*h2=nullptr;
  for (int i = 0; i < n_in; ++i) {
    if      (in_sizes[i] == NB*3*80*80*KDIM) h0 = (const float*)d_in[i];
    else if (in_sizes[i] == NB*3*40*40*KDIM) h1 = (const float*)d_in[i];
    else if (in_sizes[i] == NB*3*20*20*KDIM) h2 = (const float*)d_in[i];
  }
  char* ws = (char*)d_ws;
  unsigned* hist = (unsigned*)(ws + OFF_HIST);
  unsigned* ccnt = (unsigned*)(ws + OFF_CNT);
  unsigned long long* rnz = (unsigned long long*)(ws + OFF_RNZ);
  int* tbin      = (int*)(ws + OFF_TBIN);
  float* boxes   = (float*)(ws + OFF_BOX);
  float* sobjv   = (float*)(ws + OFF_SOBJ);
  unsigned long long* cand = (unsigned long long*)(ws + OFF_CAND);
  float* tsc     = (float*)(ws + OFF_TSC);
  int* tcls      = (int*)(ws + OFF_TCLS);
  float* traw    = (float*)(ws + OFF_TRAW);
  float* tbb     = (float*)(ws + OFF_TBB);
  float* tarea   = (float*)(ws + OFF_TAR);
  unsigned long long* keepinit = (unsigned long long*)(ws + OFF_KEEP);
  unsigned long long* sup      = (unsigned long long*)(ws + OFF_SUP);

  hipMemsetAsync(ws, 0, OFF_ZEND, stream);   // hist + ccnt + rnz

  dim3 gdec(NSLAB/4, NB);
  k_decode <<<gdec, 256, 0, stream>>>(h0, h1, h2, boxes, sobjv, hist);
  k_thresh <<<NB, 256, 0, stream>>>(hist, tbin);
  dim3 gcmp((NA + 255)/256, NB);
  k_compact<<<gcmp, 256, 0, stream>>>(h0, h1, h2, sobjv, tbin, ccnt, cand);
  k_sort   <<<NB, 1024, 0, stream>>>(cand, ccnt, boxes, tsc, tcls, traw, tbb, tarea, keepinit);
  dim3 giou(MAXN/16, NB);
  k_iou    <<<giou, 256, 0, stream>>>(tbb, tarea, sup, rnz);
  k_nms    <<<NB, 256, 0, stream>>>(keepinit, rnz, sup, tsc, tcls, traw, (float*)d_out);
}

// Round 7
// 304.973 us; speedup vs baseline: 1.3299x; 1.3299x over previous
//
#include <hip/hip_runtime.h>
#include <cstdint>

#define NB 16
#define NCL 80
#define KDIM 85
#define NA 25200
#define NBINS 1024
#define CAP 2048
#define MAXN 1024
#define NDET 300
#define NSLAB 396
#define SLOTS 416

// per (lvl*3+ai) segment tables
__device__ __constant__ float c_ancw[9] = {10.f,16.f,33.f, 30.f,62.f,59.f, 116.f,156.f,373.f};
__device__ __constant__ float c_anch[9] = {13.f,30.f,23.f, 61.f,45.f,119.f, 90.f,198.f,326.f};
__device__ __constant__ int   c_seg_a0[9]    = {0,6400,12800,19200,20800,22400,24000,24400,24800};
__device__ __constant__ int   c_seg_cells[9] = {6400,6400,6400,1600,1600,1600,400,400,400};
__device__ __constant__ int   c_seg_ww[9]    = {80,80,80,40,40,40,20,20,20};
__device__ __constant__ float c_seg_str[9]   = {8.f,8.f,8.f,16.f,16.f,16.f,32.f,32.f,32.f};
__device__ __constant__ int   c_seg_slab0[9] = {0,100,200,300,325,350,375,382,389};

__device__ __forceinline__ float sgm(float x) { return 1.0f / (1.0f + expf(-x)); }
__device__ __forceinline__ int binof(float s) {
  int b = (int)((s - 0.25f) * 1365.3334f);   // NBINS / 0.75
  return b < 0 ? 0 : (b > NBINS - 1 ? NBINS - 1 : b);
}

struct Loc { const float* base; };
__device__ __forceinline__ Loc locate(const float* h0, const float* h1, const float* h2,
                                      int img, int a) {
  Loc L; const float* hp; int cells, rel;
  if (a < 19200)      { hp=h0; cells=6400; rel=a;       }
  else if (a < 24000) { hp=h1; cells=1600; rel=a-19200; }
  else                { hp=h2; cells=400;  rel=a-24000; }
  int ai = rel / cells; int cell = rel - ai*cells;
  L.base = hp + (size_t)((img*3 + ai)*cells + cell) * KDIM;
  return L;
}

// ---- K1: LDS-staged decode (float4 staging): boxes + sobj + score histogram ----
__global__ void __launch_bounds__(256) k_decode(const float* __restrict__ h0,
    const float* __restrict__ h1, const float* __restrict__ h2,
    float* __restrict__ boxes, float* __restrict__ sobjv, unsigned* __restrict__ hist) {
  __shared__ unsigned lh[NBINS];
  __shared__ float4 buf4[(64 * KDIM) / 4];        // 21.25 KB, 16B aligned
  float* buf = (float*)buf4;
  int tid = threadIdx.x, img = blockIdx.y;
  for (int i = tid; i < NBINS; i += 256) lh[i] = 0;
  __syncthreads();
  for (int sl = 0; sl < 4; ++sl) {
    int slab = blockIdx.x * 4 + sl;          // grid.x*4 == NSLAB exactly
    int sg = 0;
    #pragma unroll
    for (int k = 1; k < 9; ++k) sg += (slab >= c_seg_slab0[k]);
    int sloc  = slab - c_seg_slab0[sg];
    int cells = c_seg_cells[sg];
    int c0    = sloc * 64;
    int ncell = min(64, cells - c0);
    const float* hp = (sg < 3) ? h0 : (sg < 6 ? h1 : h2);
    int ai = sg - (sg / 3) * 3;
    const float* src = hp + (size_t)((img*3 + ai)*cells + c0) * KDIM;
    // src is 16B-aligned: (anything*cells + sloc*64)*85 is divisible by 4 floats
    int nf4 = (ncell * KDIM) >> 2;
    __syncthreads();                          // previous slab's readers done
    const float4* src4 = (const float4*)src;
    for (int i = tid; i < nf4; i += 256) buf4[i] = src4[i];
    __syncthreads();
    int anc = tid >> 2, sub = tid & 3;
    if (anc < ncell) {
      const float* rec = &buf[anc * KDIM];
      float so = sgm(rec[4]);
      int cell = c0 + anc;
      int a = c_seg_a0[sg] + cell;
      if (sub == 0) {
        int ww = c_seg_ww[sg];
        int y = cell / ww, x = cell - y*ww;
        float sx=sgm(rec[0]), sy=sgm(rec[1]), sw=sgm(rec[2]), sh=sgm(rec[3]);
        float st = c_seg_str[sg];
        float cx = (sx*2.0f - 0.5f + (float)x) * st;
        float cy = (sy*2.0f - 0.5f + (float)y) * st;
        float tw = sw*2.0f, th = sh*2.0f;
        float wv = (tw*tw) * c_ancw[sg];
        float hv = (th*th) * c_anch[sg];
        ((float4*)boxes)[(size_t)img*NA + a] =
            make_float4(cx - wv*0.5f, cy - hv*0.5f, cx + wv*0.5f, cy + hv*0.5f);
        sobjv[(size_t)img*NA + a] = so;
      }
      if (so > 0.25f) {
        #pragma unroll 4
        for (int k = 0; k < 20; ++k) {
          float s = sgm(rec[5 + sub*20 + k]) * so;
          if (s > 0.25f) atomicAdd(&lh[binof(s)], 1u);
        }
      }
    }
  }
  __syncthreads();
  unsigned* gh = hist + (size_t)img * NBINS;
  for (int i = tid; i < NBINS; i += 256) { unsigned v = lh[i]; if (v) atomicAdd(&gh[i], v); }
}

// ---- K2: per image, largest bin T with suffix-count >= MAXN ----
__global__ void __launch_bounds__(256) k_thresh(const unsigned* __restrict__ hist,
                                                int* __restrict__ tbin) {
  int img = blockIdx.x, t = threadIdx.x;
  const unsigned* gh = hist + (size_t)img * NBINS;
  __shared__ unsigned sc[256];
  unsigned loc[4]; unsigned s = 0;
  #pragma unroll
  for (int i = 0; i < 4; ++i) { loc[i] = gh[t*4 + i]; s += loc[i]; }
  sc[t] = s; __syncthreads();
  for (int d = 1; d < 256; d <<= 1) {
    unsigned add = (t + d < 256) ? sc[t + d] : 0u;
    __syncthreads(); sc[t] += add; __syncthreads();
  }
  unsigned inc = sc[t];
  unsigned excl = inc - s;
  if (excl < MAXN && inc >= MAXN) {
    unsigned cum = excl; int myT = 0;
    #pragma unroll
    for (int i = 3; i >= 0; --i) { cum += loc[i]; if (cum >= MAXN) { myT = t*4 + i; break; } }
    tbin[img] = myT;
  }
  if (t == 0 && sc[0] < MAXN) tbin[img] = 0;
}

// ---- K3: sobj-gated cooperative compaction, two-level reservation ----
__global__ void __launch_bounds__(256) k_compact(const float* __restrict__ h0,
    const float* __restrict__ h1, const float* __restrict__ h2,
    const float* __restrict__ sobjv, const int* __restrict__ tbin,
    unsigned* __restrict__ ccnt, unsigned long long* __restrict__ cand) {
  __shared__ unsigned long long lbuf[CAP];     // 16 KB block-local candidate buffer
  __shared__ unsigned lcnt, gbase;
  int img = blockIdx.y, tid = threadIdx.x;
  if (tid == 0) lcnt = 0;
  __syncthreads();
  int a = blockIdx.x * 256 + tid;
  int lane = tid & 63;
  int T = tbin[img];
  float gthr = 0.25f + (float)(T - 1) * (0.75f / (float)NBINS);  // one-bin slack
  float so = 0.0f; bool pass = false;
  if (a < NA) { so = sobjv[(size_t)img*NA + a]; pass = so > gthr; }
  unsigned long long m = __ballot(pass);
  while (m) {
    int srcl = __builtin_ctzll(m); m &= m - 1;
    int aa   = __shfl(a, srcl);
    float sso = __shfl(so, srcl);
    Loc L = locate(h0, h1, h2, img, aa);
    for (int c = lane; c < NCL; c += 64) {
      float s = sgm(L.base[5 + c]) * sso;
      if (s > 0.25f && binof(s) >= T) {
        unsigned p = atomicAdd(&lcnt, 1u);     // LDS atomic: no XCD ping-pong
        if (p < CAP) {
          unsigned idx = (unsigned)(aa * NCL + c);
          lbuf[p] = ((unsigned long long)__float_as_uint(s) << 32) | (unsigned)(~idx);
        }
      }
    }
  }
  __syncthreads();
  unsigned n = min(lcnt, (unsigned)CAP);
  if (tid == 0) gbase = atomicAdd(&ccnt[img], n);   // ONE global atomic per block
  __syncthreads();
  unsigned b = gbase;
  for (unsigned i = tid; i < n; i += 256) {
    unsigned p = b + i;
    if (p < CAP) cand[(size_t)img*CAP + p] = lbuf[i];
  }
}

// ---- K4: per-image bitonic sort (desc), build top-1024 arrays ----
__global__ void __launch_bounds__(1024) k_sort(const unsigned long long* __restrict__ cand,
    const unsigned* __restrict__ ccnt, const float* __restrict__ boxes,
    float* __restrict__ tsc, int* __restrict__ tcls, float* __restrict__ traw,
    float* __restrict__ tbb, float* __restrict__ tarea,
    unsigned long long* __restrict__ keepinit) {
  __shared__ unsigned long long key[CAP];
  int img = blockIdx.x, t = threadIdx.x;
  int n = (int)min(ccnt[img], (unsigned)CAP);
  const unsigned long long* cb = cand + (size_t)img*CAP;
  key[t]        = (t < n)        ? cb[t]        : 0ull;
  key[t + 1024] = (t + 1024 < n) ? cb[t + 1024] : 0ull;
  __syncthreads();
  for (int k = 2; k <= CAP; k <<= 1) {
    for (int j = k >> 1; j > 0; j >>= 1) {
      #pragma unroll
      for (int eo = 0; eo < 2; ++eo) {
        int e = t + eo*1024;
        int l = e ^ j;
        if (l > e) {
          unsigned long long va = key[e], vb = key[l];
          bool up = (e & k) == 0;
          if (up ? (va < vb) : (va > vb)) { key[e] = vb; key[l] = va; }
        }
      }
      __syncthreads();
    }
  }
  unsigned long long kk = key[t];
  float s = __uint_as_float((unsigned)(kk >> 32));
  unsigned idx = ~(unsigned)kk;
  float b0=0,b1=0,b2=0,b3=0, bb0=0,bb1=0,bb2=0,bb3=0, ar=0; int cls=0;
  if (s > 0.0f) {
    unsigned anc = idx / NCL; cls = (int)(idx - anc*NCL);
    const float4 bp = ((const float4*)boxes)[(size_t)img*NA + anc];
    b0=bp.x; b1=bp.y; b2=bp.z; b3=bp.w;
    float off = (float)cls * 4096.0f;
    bb0=b0+off; bb1=b1+off; bb2=b2+off; bb3=b3+off;
    ar = (bb2-bb0)*(bb3-bb1);
  }
  int o = img*MAXN + t;
  tsc[o] = s; tcls[o] = cls; tarea[o] = ar;
  ((float4*)traw)[o] = make_float4(b0,b1,b2,b3);
  ((float4*)tbb)[o]  = make_float4(bb0,bb1,bb2,bb3);
  unsigned long long ball = __ballot(s > 0.0f);
  if ((t & 63) == 0) keepinit[img*16 + (t >> 6)] = ball;
}

// ---- K5: suppression bit matrix + block-aggregated row non-empty mask ----
__global__ void __launch_bounds__(256) k_iou(const float* __restrict__ tbb,
    const float* __restrict__ tarea, unsigned long long* __restrict__ sup,
    unsigned long long* __restrict__ rnz) {
  __shared__ float jx1[MAXN], jy1[MAXN], jx2[MAXN], jy2[MAXN], jar[MAXN];
  __shared__ unsigned rowflag;
  int img = blockIdx.y, t = threadIdx.x;
  if (t == 0) rowflag = 0;
  const float4* bbb = (const float4*)(tbb + (size_t)img*MAXN*4);
  const float* aab = tarea + (size_t)img*MAXN;
  for (int i = t; i < MAXN; i += 256) {
    float4 v = bbb[i];
    jx1[i]=v.x; jy1[i]=v.y; jx2[i]=v.z; jy2[i]=v.w; jar[i]=aab[i];
  }
  __syncthreads();
  int il = t >> 4, c = t & 15;
  int i = blockIdx.x*16 + il;
  float x1=jx1[i], y1=jy1[i], x2=jx2[i], y2=jy2[i], ai=jar[i];
  unsigned long long bits = 0;
  for (int l = 0; l < 64; ++l) {
    int ll = (l + c) & 63;            // rotate to spread LDS banks
    int j = c*64 + ll;
    if (j > i) {
      float ltx = fmaxf(x1, jx1[j]), lty = fmaxf(y1, jy1[j]);
      float rbx = fminf(x2, jx2[j]), rby = fminf(y2, jy2[j]);
      float w = fmaxf(rbx - ltx, 0.0f), h = fmaxf(rby - lty, 0.0f);
      float inter = w*h;
      float iou = inter / (ai + jar[j] - inter + 1e-7f);
      if (iou > 0.45f) bits |= (1ull << ll);
    }
  }
  sup[((size_t)img*MAXN + i)*16 + c] = bits;
  if (bits) atomicOr(&rowflag, 1u << il);      // LDS aggregate
  __syncthreads();
  if (t == 0 && rowflag) {
    int i0 = blockIdx.x * 16;                   // 16-aligned => single 64-bit word
    atomicOr(&rnz[img*16 + (i0 >> 6)], (unsigned long long)rowflag << (i0 & 63));
  }
}

// ---- K6: LDS-staged sequential NMS + output ----
__global__ void __launch_bounds__(256) k_nms(const unsigned long long* __restrict__ keepinit,
    const unsigned long long* __restrict__ rnz, const unsigned long long* __restrict__ sup,
    const float* __restrict__ tsc, const int* __restrict__ tcls,
    const float* __restrict__ traw, float* __restrict__ out) {
  __shared__ unsigned long long rows[SLOTS*16];
  __shared__ unsigned short slotof[MAXN];
  __shared__ unsigned short rowof[SLOTS];
  __shared__ int scanbuf[256];
  __shared__ int order[MAXN];
  __shared__ unsigned long long s_rnz[16], s_keep[16];
  int img = blockIdx.x, tid = threadIdx.x;
  if (tid < 16) { s_rnz[tid] = rnz[img*16 + tid]; s_keep[tid] = keepinit[img*16 + tid]; }
  __syncthreads();
  // slot assignment: thread t covers rows 4t..4t+3
  unsigned nib = (unsigned)((s_rnz[tid >> 4] >> ((tid & 15)*4)) & 0xFull);
  int cnt4 = __popc(nib);
  scanbuf[tid] = cnt4; __syncthreads();
  for (int d = 1; d < 256; d <<= 1) {
    int add = (tid >= d) ? scanbuf[tid - d] : 0;
    __syncthreads(); scanbuf[tid] += add; __syncthreads();
  }
  int p = scanbuf[tid] - cnt4;
  #pragma unroll
  for (int k = 0; k < 4; ++k) {
    int r = tid*4 + k;
    if ((nib >> k) & 1) {
      if (p < SLOTS) { slotof[r] = (unsigned short)p; rowof[p] = (unsigned short)r; }
      else slotof[r] = 0xFFFF;
      ++p;
    } else slotof[r] = 0xFFFF;
  }
  __syncthreads();
  int nstage = min(scanbuf[255], SLOTS);
  for (int k = tid; k < nstage*16; k += 256)
    rows[k] = sup[((size_t)img*MAXN + rowof[k >> 4])*16 + (k & 15)];
  __syncthreads();
  if (tid < 64) {
    int lane = tid;
    unsigned long long keep = (lane < 16) ? s_keep[lane] : 0ull;
    unsigned long long rem  = (lane < 16) ? (s_keep[lane] & s_rnz[lane]) : 0ull;
    while (true) {
      int candi = MAXN;
      if (lane < 16 && rem) candi = lane*64 + __builtin_ctzll(rem);
      #pragma unroll
      for (int o = 32; o; o >>= 1) candi = min(candi, __shfl_xor(candi, o));
      if (candi >= MAXN) break;
      int sl = slotof[candi];
      unsigned long long row = 0;
      if (lane < 16)
        row = (sl != 0xFFFF) ? rows[sl*16 + lane]
                             : sup[((size_t)img*MAXN + candi)*16 + lane];
      keep &= ~row; rem &= ~row;
      if (lane == (candi >> 6)) rem &= ~(1ull << (candi & 63));
    }
    int cnt = (lane < 16) ? __popcll(keep) : 0;
    int inc = cnt;
    for (int d = 1; d < 64; d <<= 1) { int y = __shfl_up(inc, d); if (lane >= d) inc += y; }
    int total = __shfl(inc, 63);
    int base = inc - cnt;
    if (lane < 16) {
      unsigned long long mm = keep; int q = base;
      while (mm) { int b = __builtin_ctzll(mm); mm &= mm - 1; order[q++] = lane*64 + b; }
    }
    for (int r = lane; r < NDET; r += 64) {
      float4 fb = make_float4(0,0,0,0); float fs = 0.0f; float fl = -1.0f;
      if (r < total) {
        int o = img*MAXN + order[r];
        fs = tsc[o];
        fb = ((const float4*)traw)[o];
        fl = (float)tcls[o];
      }
      int ob = img*NDET + r;
      ((float4*)out)[ob] = fb;
      out[(size_t)NB*NDET*4 + ob] = fs;
      out[(size_t)NB*NDET*5 + ob] = fl;   // labels as FLOAT values (harness reads f32)
    }
  }
}

// ---- workspace layout (zero-init region first) ----
constexpr size_t AL(size_t x){ return (x + 255) & ~size_t(255); }
constexpr size_t OFF_HIST = 0;                                      // 16*1024*4
constexpr size_t OFF_CNT  = AL(OFF_HIST + (size_t)NB*NBINS*4);      // 16*4
constexpr size_t OFF_RNZ  = AL(OFF_CNT  + (size_t)NB*4);            // 16*16*8
constexpr size_t OFF_ZEND = AL(OFF_RNZ  + (size_t)NB*16*8);
constexpr size_t OFF_TBIN = OFF_ZEND;
constexpr size_t OFF_BOX  = AL(OFF_TBIN + (size_t)NB*4);
constexpr size_t OFF_SOBJ = AL(OFF_BOX  + (size_t)NB*NA*4*4);
constexpr size_t OFF_CAND = AL(OFF_SOBJ + (size_t)NB*NA*4);
constexpr size_t OFF_TSC  = AL(OFF_CAND + (size_t)NB*CAP*8);
constexpr size_t OFF_TCLS = AL(OFF_TSC  + (size_t)NB*MAXN*4);
constexpr size_t OFF_TRAW = AL(OFF_TCLS + (size_t)NB*MAXN*4);
constexpr size_t OFF_TBB  = AL(OFF_TRAW + (size_t)NB*MAXN*16);
constexpr size_t OFF_TAR  = AL(OFF_TBB  + (size_t)NB*MAXN*16);
constexpr size_t OFF_KEEP = AL(OFF_TAR  + (size_t)NB*MAXN*4);
constexpr size_t OFF_SUP  = AL(OFF_KEEP + (size_t)NB*16*8);

extern "C" void kernel_launch(void* const* d_in, const int* in_sizes, int n_in,
                              void* d_out, int out_size, void* d_ws, size_t ws_size,
                              hipStream_t stream) {
  const float *h0=nullptr,*h1=nullptr,*h2=nullptr;
  for (int i = 0; i < n_in; ++i) {
    if      (in_sizes[i] == NB*3*80*80*KDIM) h0 = (const float*)d_in[i];
    else if (in_sizes[i] == NB*3*40*40*KDIM) h1 = (const float*)d_in[i];
    else if (in_sizes[i] == NB*3*20*20*KDIM) h2 = (const float*)d_in[i];
  }
  char* ws = (char*)d_ws;
  unsigned* hist = (unsigned*)(ws + OFF_HIST);
  unsigned* ccnt = (unsigned*)(ws + OFF_CNT);
  unsigned long long* rnz = (unsigned long long*)(ws + OFF_RNZ);
  int* tbin      = (int*)(ws + OFF_TBIN);
  float* boxes   = (float*)(ws + OFF_BOX);
  float* sobjv   = (float*)(ws + OFF_SOBJ);
  unsigned long long* cand = (unsigned long long*)(ws + OFF_CAND);
  float* tsc     = (float*)(ws + OFF_TSC);
  int* tcls      = (int*)(ws + OFF_TCLS);
  float* traw    = (float*)(ws + OFF_TRAW);
  float* tbb     = (float*)(ws + OFF_TBB);
  float* tarea   = (float*)(ws + OFF_TAR);
  unsigned long long* keepinit = (unsigned long long*)(ws + OFF_KEEP);
  unsigned long long* sup      = (unsigned long long*)(ws + OFF_SUP);

  hipMemsetAsync(ws, 0, OFF_ZEND, stream);   // hist + ccnt + rnz

  dim3 gdec(NSLAB/4, NB);
  k_decode <<<gdec, 256, 0, stream>>>(h0, h1, h2, boxes, sobjv, hist);
  k_thresh <<<NB, 256, 0, stream>>>(hist, tbin);
  dim3 gcmp((NA + 255)/256, NB);
  k_compact<<<gcmp, 256, 0, stream>>>(h0, h1, h2, sobjv, tbin, ccnt, cand);
  k_sort   <<<NB, 1024, 0, stream>>>(cand, ccnt, boxes, tsc, tcls, traw, tbb, tarea, keepinit);
  dim3 giou(MAXN/16, NB);
  k_iou    <<<giou, 256, 0, stream>>>(tbb, tarea, sup, rnz);
  k_nms    <<<NB, 256, 0, stream>>>(keepinit, rnz, sup, tsc, tcls, traw, (float*)d_out);
}

// Round 9
// 290.857 us; speedup vs baseline: 1.3945x; 1.0485x over previous
//
#include <hip/hip_runtime.h>
#include <cstdint>

#define NB 16
#define NCL 80
#define KDIM 85
#define NA 25200
#define NBINS 256
#define CAP 2048
#define MAXN 1024
#define NDET 300
#define NSLAB 396
#define SLOTS 416

// per (lvl*3+ai) segment tables
__device__ __constant__ float c_ancw[9] = {10.f,16.f,33.f, 30.f,62.f,59.f, 116.f,156.f,373.f};
__device__ __constant__ float c_anch[9] = {13.f,30.f,23.f, 61.f,45.f,119.f, 90.f,198.f,326.f};
__device__ __constant__ int   c_seg_a0[9]    = {0,6400,12800,19200,20800,22400,24000,24400,24800};
__device__ __constant__ int   c_seg_cells[9] = {6400,6400,6400,1600,1600,1600,400,400,400};
__device__ __constant__ int   c_seg_ww[9]    = {80,80,80,40,40,40,20,20,20};
__device__ __constant__ float c_seg_str[9]   = {8.f,8.f,8.f,16.f,16.f,16.f,32.f,32.f,32.f};
__device__ __constant__ int   c_seg_slab0[9] = {0,100,200,300,325,350,375,382,389};

__device__ __forceinline__ float sgm(float x) { return 1.0f / (1.0f + expf(-x)); }
__device__ __forceinline__ int binof(float s) {
  int b = (int)((s - 0.25f) * 341.33334f);   // NBINS / 0.75
  return b < 0 ? 0 : (b > NBINS - 1 ? NBINS - 1 : b);
}

struct Loc { const float* base; };
__device__ __forceinline__ Loc locate(const float* h0, const float* h1, const float* h2,
                                      int img, int a) {
  Loc L; const float* hp; int cells, rel;
  if (a < 19200)      { hp=h0; cells=6400; rel=a;       }
  else if (a < 24000) { hp=h1; cells=1600; rel=a-19200; }
  else                { hp=h2; cells=400;  rel=a-24000; }
  int ai = rel / cells; int cell = rel - ai*cells;
  L.base = hp + (size_t)((img*3 + ai)*cells + cell) * KDIM;
  return L;
}

// ---- K1: LDS-staged decode (float4 staging): boxes + sobj + score histogram ----
// Logit-space prefilter: sgm(c)*so > 0.25  <=>  c > logit(0.25/so); computed once
// per anchor with -0.05 conservative slack, exact s>0.25 check retained after.
__global__ void __launch_bounds__(256) k_decode(const float* __restrict__ h0,
    const float* __restrict__ h1, const float* __restrict__ h2,
    float* __restrict__ boxes, float* __restrict__ sobjv, unsigned* __restrict__ hist) {
  __shared__ unsigned lh[NBINS];
  __shared__ float4 buf4[(64 * KDIM) / 4];        // 21.25 KB, 16B aligned
  float* buf = (float*)buf4;
  int tid = threadIdx.x, img = blockIdx.y;
  for (int i = tid; i < NBINS; i += 256) lh[i] = 0;
  __syncthreads();
  for (int sl = 0; sl < 4; ++sl) {
    int slab = blockIdx.x * 4 + sl;          // grid.x*4 == NSLAB exactly
    int sg = 0;
    #pragma unroll
    for (int k = 1; k < 9; ++k) sg += (slab >= c_seg_slab0[k]);
    int sloc  = slab - c_seg_slab0[sg];
    int cells = c_seg_cells[sg];
    int c0    = sloc * 64;
    int ncell = min(64, cells - c0);
    const float* hp = (sg < 3) ? h0 : (sg < 6 ? h1 : h2);
    int ai = sg - (sg / 3) * 3;
    const float* src = hp + (size_t)((img*3 + ai)*cells + c0) * KDIM;
    int nf4 = (ncell * KDIM) >> 2;
    __syncthreads();                          // previous slab's readers done
    const float4* src4 = (const float4*)src;
    for (int i = tid; i < nf4; i += 256) buf4[i] = src4[i];
    __syncthreads();
    int anc = tid >> 2, sub = tid & 3;
    if (anc < ncell) {
      const float* rec = &buf[anc * KDIM];
      float so = sgm(rec[4]);
      int cell = c0 + anc;
      int a = c_seg_a0[sg] + cell;
      if (sub == 0) {
        int ww = c_seg_ww[sg];
        int y;                                  // constant-divisor paths
        if (ww == 80) y = cell / 80; else if (ww == 40) y = cell / 40; else y = cell / 20;
        int x = cell - y*ww;
        float sx=sgm(rec[0]), sy=sgm(rec[1]), sw=sgm(rec[2]), sh=sgm(rec[3]);
        float st = c_seg_str[sg];
        float cx = (sx*2.0f - 0.5f + (float)x) * st;
        float cy = (sy*2.0f - 0.5f + (float)y) * st;
        float tw = sw*2.0f, th = sh*2.0f;
        float wv = (tw*tw) * c_ancw[sg];
        float hv = (th*th) * c_anch[sg];
        ((float4*)boxes)[(size_t)img*NA + a] =
            make_float4(cx - wv*0.5f, cy - hv*0.5f, cx + wv*0.5f, cy + hv*0.5f);
        sobjv[(size_t)img*NA + a] = so;
      }
      if (so > 0.25f) {
        float q = 0.25f / so;                  // < 1 since so > 0.25
        float cth = logf(q / (1.0f - q)) - 0.05f;   // conservative slack
        #pragma unroll 4
        for (int k = 0; k < 20; ++k) {
          float c = rec[5 + sub*20 + k];
          if (c > cth) {
            float s = sgm(c) * so;
            if (s > 0.25f) atomicAdd(&lh[binof(s)], 1u);   // exact check kept
          }
        }
      }
    }
  }
  __syncthreads();
  unsigned* gh = hist + (size_t)img * NBINS;
  for (int i = tid; i < NBINS; i += 256) { unsigned v = lh[i]; if (v) atomicAdd(&gh[i], v); }
}

// ---- K2: per image, largest bin T with suffix-count >= MAXN (256 bins) ----
__global__ void __launch_bounds__(256) k_thresh(const unsigned* __restrict__ hist,
                                                int* __restrict__ tbin) {
  int img = blockIdx.x, t = threadIdx.x;
  __shared__ unsigned sc[256];
  unsigned s = hist[(size_t)img*NBINS + t];
  sc[t] = s; __syncthreads();
  for (int d = 1; d < 256; d <<= 1) {
    unsigned add = (t + d < 256) ? sc[t + d] : 0u;
    __syncthreads(); sc[t] += add; __syncthreads();
  }
  unsigned inc = sc[t];          // suffix sum from t
  unsigned excl = inc - s;       // suffix sum from t+1
  if (excl < MAXN && inc >= MAXN) tbin[img] = t;
  if (t == 0 && sc[0] < MAXN) tbin[img] = 0;
}

// ---- K3: sobj-gated cooperative compaction, two-level reservation ----
__global__ void __launch_bounds__(256) k_compact(const float* __restrict__ h0,
    const float* __restrict__ h1, const float* __restrict__ h2,
    const float* __restrict__ sobjv, const int* __restrict__ tbin,
    unsigned* __restrict__ ccnt, unsigned long long* __restrict__ cand) {
  __shared__ unsigned long long lbuf[CAP];     // 16 KB block-local candidate buffer
  __shared__ unsigned lcnt, gbase;
  int img = blockIdx.y, tid = threadIdx.x;
  if (tid == 0) lcnt = 0;
  __syncthreads();
  int a = blockIdx.x * 256 + tid;
  int lane = tid & 63;
  int T = tbin[img];
  float gthr = 0.25f + (float)(T - 1) * (0.75f / (float)NBINS);  // one-bin slack
  float so = 0.0f; bool pass = false;
  if (a < NA) { so = sobjv[(size_t)img*NA + a]; pass = so > gthr; }
  unsigned long long m = __ballot(pass);
  while (m) {
    int srcl = __builtin_ctzll(m); m &= m - 1;
    int aa   = __shfl(a, srcl);
    float sso = __shfl(so, srcl);
    Loc L = locate(h0, h1, h2, img, aa);
    for (int c = lane; c < NCL; c += 64) {
      float s = sgm(L.base[5 + c]) * sso;
      if (s > 0.25f && binof(s) >= T) {
        unsigned p = atomicAdd(&lcnt, 1u);     // LDS atomic: no XCD ping-pong
        if (p < CAP) {
          unsigned idx = (unsigned)(aa * NCL + c);
          lbuf[p] = ((unsigned long long)__float_as_uint(s) << 32) | (unsigned)(~idx);
        }
      }
    }
  }
  __syncthreads();
  unsigned n = min(lcnt, (unsigned)CAP);
  if (tid == 0) gbase = atomicAdd(&ccnt[img], n);   // ONE global atomic per block
  __syncthreads();
  unsigned b = gbase;
  for (unsigned i = tid; i < n; i += 256) {
    unsigned p = b + i;
    if (p < CAP) cand[(size_t)img*CAP + p] = lbuf[i];
  }
}

// ---- K4: per-image bitonic sort (desc), build top-1024 arrays ----
__global__ void __launch_bounds__(1024) k_sort(const unsigned long long* __restrict__ cand,
    const unsigned* __restrict__ ccnt, const float* __restrict__ boxes,
    float* __restrict__ tsc, int* __restrict__ tcls, float* __restrict__ traw,
    float* __restrict__ tbb, float* __restrict__ tarea,
    unsigned long long* __restrict__ keepinit) {
  __shared__ unsigned long long key[CAP];
  int img = blockIdx.x, t = threadIdx.x;
  int n = (int)min(ccnt[img], (unsigned)CAP);
  const unsigned long long* cb = cand + (size_t)img*CAP;
  key[t]        = (t < n)        ? cb[t]        : 0ull;
  key[t + 1024] = (t + 1024 < n) ? cb[t + 1024] : 0ull;
  __syncthreads();
  for (int k = 2; k <= CAP; k <<= 1) {
    for (int j = k >> 1; j > 0; j >>= 1) {
      #pragma unroll
      for (int eo = 0; eo < 2; ++eo) {
        int e = t + eo*1024;
        int l = e ^ j;
        if (l > e) {
          unsigned long long va = key[e], vb = key[l];
          bool up = (e & k) == 0;
          if (up ? (va < vb) : (va > vb)) { key[e] = vb; key[l] = va; }
        }
      }
      __syncthreads();
    }
  }
  unsigned long long kk = key[t];
  float s = __uint_as_float((unsigned)(kk >> 32));
  unsigned idx = ~(unsigned)kk;
  float b0=0,b1=0,b2=0,b3=0, bb0=0,bb1=0,bb2=0,bb3=0, ar=0; int cls=0;
  if (s > 0.0f) {
    unsigned anc = idx / NCL; cls = (int)(idx - anc*NCL);
    const float4 bp = ((const float4*)boxes)[(size_t)img*NA + anc];
    b0=bp.x; b1=bp.y; b2=bp.z; b3=bp.w;
    float off = (float)cls * 4096.0f;
    bb0=b0+off; bb1=b1+off; bb2=b2+off; bb3=b3+off;
    ar = (bb2-bb0)*(bb3-bb1);
  }
  int o = img*MAXN + t;
  tsc[o] = s; tcls[o] = cls; tarea[o] = ar;
  ((float4*)traw)[o] = make_float4(b0,b1,b2,b3);
  ((float4*)tbb)[o]  = make_float4(bb0,bb1,bb2,bb3);
  unsigned long long ball = __ballot(s > 0.0f);
  if ((t & 63) == 0) keepinit[img*16 + (t >> 6)] = ball;
}

// ---- K5: suppression bit matrix + block-aggregated row non-empty mask ----
__global__ void __launch_bounds__(256) k_iou(const float* __restrict__ tbb,
    const float* __restrict__ tarea, unsigned long long* __restrict__ sup,
    unsigned long long* __restrict__ rnz) {
  __shared__ float jx1[MAXN], jy1[MAXN], jx2[MAXN], jy2[MAXN], jar[MAXN];
  __shared__ unsigned rowflag;
  int img = blockIdx.y, t = threadIdx.x;
  if (t == 0) rowflag = 0;
  const float4* bbb = (const float4*)(tbb + (size_t)img*MAXN*4);
  const float* aab = tarea + (size_t)img*MAXN;
  for (int i = t; i < MAXN; i += 256) {
    float4 v = bbb[i];
    jx1[i]=v.x; jy1[i]=v.y; jx2[i]=v.z; jy2[i]=v.w; jar[i]=aab[i];
  }
  __syncthreads();
  int il = t >> 4, c = t & 15;
  int i = blockIdx.x*16 + il;
  float x1=jx1[i], y1=jy1[i], x2=jx2[i], y2=jy2[i], ai=jar[i];
  unsigned long long bits = 0;
  for (int l = 0; l < 64; ++l) {
    int ll = (l + c) & 63;            // rotate to spread LDS banks
    int j = c*64 + ll;
    if (j > i) {
      float ltx = fmaxf(x1, jx1[j]), lty = fmaxf(y1, jy1[j]);
      float rbx = fminf(x2, jx2[j]), rby = fminf(y2, jy2[j]);
      float w = fmaxf(rbx - ltx, 0.0f), h = fmaxf(rby - lty, 0.0f);
      float inter = w*h;
      float iou = inter / (ai + jar[j] - inter + 1e-7f);
      if (iou > 0.45f) bits |= (1ull << ll);
    }
  }
  sup[((size_t)img*MAXN + i)*16 + c] = bits;
  if (bits) atomicOr(&rowflag, 1u << il);      // LDS aggregate
  __syncthreads();
  if (t == 0 && rowflag) {
    int i0 = blockIdx.x * 16;                   // 16-aligned => single 64-bit word
    atomicOr(&rnz[img*16 + (i0 >> 6)], (unsigned long long)rowflag << (i0 & 63));
  }
}

// ---- K6: LDS-staged sequential NMS + output ----
__global__ void __launch_bounds__(256) k_nms(const unsigned long long* __restrict__ keepinit,
    const unsigned long long* __restrict__ rnz, const unsigned long long* __restrict__ sup,
    const float* __restrict__ tsc, const int* __restrict__ tcls,
    const float* __restrict__ traw, float* __restrict__ out) {
  __shared__ unsigned long long rows[SLOTS*16];
  __shared__ unsigned short slotof[MAXN];
  __shared__ unsigned short rowof[SLOTS];
  __shared__ int scanbuf[256];
  __shared__ int order[MAXN];
  __shared__ unsigned long long s_rnz[16], s_keep[16];
  int img = blockIdx.x, tid = threadIdx.x;
  if (tid < 16) { s_rnz[tid] = rnz[img*16 + tid]; s_keep[tid] = keepinit[img*16 + tid]; }
  __syncthreads();
  // slot assignment: thread t covers rows 4t..4t+3
  unsigned nib = (unsigned)((s_rnz[tid >> 4] >> ((tid & 15)*4)) & 0xFull);
  int cnt4 = __popc(nib);
  scanbuf[tid] = cnt4; __syncthreads();
  for (int d = 1; d < 256; d <<= 1) {
    int add = (tid >= d) ? scanbuf[tid - d] : 0;
    __syncthreads(); scanbuf[tid] += add; __syncthreads();
  }
  int p = scanbuf[tid] - cnt4;
  #pragma unroll
  for (int k = 0; k < 4; ++k) {
    int r = tid*4 + k;
    if ((nib >> k) & 1) {
      if (p < SLOTS) { slotof[r] = (unsigned short)p; rowof[p] = (unsigned short)r; }
      else slotof[r] = 0xFFFF;
      ++p;
    } else slotof[r] = 0xFFFF;
  }
  __syncthreads();
  int nstage = min(scanbuf[255], SLOTS);
  for (int k = tid; k < nstage*16; k += 256)
    rows[k] = sup[((size_t)img*MAXN + rowof[k >> 4])*16 + (k & 15)];
  __syncthreads();
  if (tid < 64) {
    int lane = tid;
    unsigned long long keep = (lane < 16) ? s_keep[lane] : 0ull;
    unsigned long long rem  = (lane < 16) ? (s_keep[lane] & s_rnz[lane]) : 0ull;
    while (true) {
      int candi = MAXN;
      if (lane < 16 && rem) candi = lane*64 + __builtin_ctzll(rem);
      #pragma unroll
      for (int o = 32; o; o >>= 1) candi = min(candi, __shfl_xor(candi, o));
      if (candi >= MAXN) break;
      int sl = slotof[candi];
      unsigned long long row = 0;
      if (lane < 16)
        row = (sl != 0xFFFF) ? rows[sl*16 + lane]
                             : sup[((size_t)img*MAXN + candi)*16 + lane];
      keep &= ~row; rem &= ~row;
      if (lane == (candi >> 6)) rem &= ~(1ull << (candi & 63));
    }
    int cnt = (lane < 16) ? __popcll(keep) : 0;
    int inc = cnt;
    for (int d = 1; d < 64; d <<= 1) { int y = __shfl_up(inc, d); if (lane >= d) inc += y; }
    int total = __shfl(inc, 63);
    int base = inc - cnt;
    if (lane < 16) {
      unsigned long long mm = keep; int q = base;
      while (mm) { int b = __builtin_ctzll(mm); mm &= mm - 1; order[q++] = lane*64 + b; }
    }
    for (int r = lane; r < NDET; r += 64) {
      float4 fb = make_float4(0,0,0,0); float fs = 0.0f; float fl = -1.0f;
      if (r < total) {
        int o = img*MAXN + order[r];
        fs = tsc[o];
        fb = ((const float4*)traw)[o];
        fl = (float)tcls[o];
      }
      int ob = img*NDET + r;
      ((float4*)out)[ob] = fb;
      out[(size_t)NB*NDET*4 + ob] = fs;
      out[(size_t)NB*NDET*5 + ob] = fl;   // labels as FLOAT values (harness reads f32)
    }
  }
}

// ---- workspace layout (zero-init region first) ----
constexpr size_t AL(size_t x){ return (x + 255) & ~size_t(255); }
constexpr size_t OFF_HIST = 0;                                      // 16*256*4
constexpr size_t OFF_CNT  = AL(OFF_HIST + (size_t)NB*NBINS*4);      // 16*4
constexpr size_t OFF_RNZ  = AL(OFF_CNT  + (size_t)NB*4);            // 16*16*8
constexpr size_t OFF_ZEND = AL(OFF_RNZ  + (size_t)NB*16*8);
constexpr size_t OFF_TBIN = OFF_ZEND;
constexpr size_t OFF_BOX  = AL(OFF_TBIN + (size_t)NB*4);
constexpr size_t OFF_SOBJ = AL(OFF_BOX  + (size_t)NB*NA*4*4);
constexpr size_t OFF_CAND = AL(OFF_SOBJ + (size_t)NB*NA*4);
constexpr size_t OFF_TSC  = AL(OFF_CAND + (size_t)NB*CAP*8);
constexpr size_t OFF_TCLS = AL(OFF_TSC  + (size_t)NB*MAXN*4);
constexpr size_t OFF_TRAW = AL(OFF_TCLS + (size_t)NB*MAXN*4);
constexpr size_t OFF_TBB  = AL(OFF_TRAW + (size_t)NB*MAXN*16);
constexpr size_t OFF_TAR  = AL(OFF_TBB  + (size_t)NB*MAXN*16);
constexpr size_t OFF_KEEP = AL(OFF_TAR  + (size_t)NB*MAXN*4);
constexpr size_t OFF_SUP  = AL(OFF_KEEP + (size_t)NB*16*8);

extern "C" void kernel_launch(void* const* d_in, const int* in_sizes, int n_in,
                              void* d_out, int out_size, void* d_ws, size_t ws_size,
                              hipStream_t stream) {
  const float *h0=nullptr,*h1=nullptr,*h2=nullptr;
  for (int i = 0; i < n_in; ++i) {
    if      (in_sizes[i] == NB*3*80*80*KDIM) h0 = (const float*)d_in[i];
    else if (in_sizes[i] == NB*3*40*40*KDIM) h1 = (const float*)d_in[i];
    else if (in_sizes[i] == NB*3*20*20*KDIM) h2 = (const float*)d_in[i];
  }
  char* ws = (char*)d_ws;
  unsigned* hist = (unsigned*)(ws + OFF_HIST);
  unsigned* ccnt = (unsigned*)(ws + OFF_CNT);
  unsigned long long* rnz = (unsigned long long*)(ws + OFF_RNZ);
  int* tbin      = (int*)(ws + OFF_TBIN);
  float* boxes   = (float*)(ws + OFF_BOX);
  float* sobjv   = (float*)(ws + OFF_SOBJ);
  unsigned long long* cand = (unsigned long long*)(ws + OFF_CAND);
  float* tsc     = (float*)(ws + OFF_TSC);
  int* tcls      = (int*)(ws + OFF_TCLS);
  float* traw    = (float*)(ws + OFF_TRAW);
  float* tbb     = (float*)(ws + OFF_TBB);
  float* tarea   = (float*)(ws + OFF_TAR);
  unsigned long long* keepinit = (unsigned long long*)(ws + OFF_KEEP);
  unsigned long long* sup      = (unsigned long long*)(ws + OFF_SUP);

  hipMemsetAsync(ws, 0, OFF_ZEND, stream);   // hist + ccnt + rnz

  dim3 gdec(NSLAB/4, NB);
  k_decode <<<gdec, 256, 0, stream>>>(h0, h1, h2, boxes, sobjv, hist);
  k_thresh <<<NB, 256, 0, stream>>>(hist, tbin);
  dim3 gcmp((NA + 255)/256, NB);
  k_compact<<<gcmp, 256, 0, stream>>>(h0, h1, h2, sobjv, tbin, ccnt, cand);
  k_sort   <<<NB, 1024, 0, stream>>>(cand, ccnt, boxes, tsc, tcls, traw, tbb, tarea, keepinit);
  dim3 giou(MAXN/16, NB);
  k_iou    <<<giou, 256, 0, stream>>>(tbb, tarea, sup, rnz);
  k_nms    <<<NB, 256, 0, stream>>>(keepinit, rnz, sup, tsc, tcls, traw, (float*)d_out);
}